// Round 13
// baseline (12.576 us; speedup 1.0000x reference)
//
#include <hip/hip_runtime.h>

#define SDF_THR 5e-5f
#define TRACE_ITERS 10
#define N_STEPS 100
#define N_ROOTFIND 8
#define QGUARD 1e-5f

typedef float f32x2 __attribute__((ext_vector_type(2)));

// raw v_sqrt_f32 (~1 ulp)
__device__ __forceinline__ float fast_sqrtf(float x) {
#if __has_builtin(__builtin_amdgcn_sqrtf)
    return __builtin_amdgcn_sqrtf(x);
#else
    return sqrtf(x);
#endif
}
// raw v_rcp_f32 (~1 ulp) — used ONLY for window-center estimates (slack >> error)
__device__ __forceinline__ float fast_rcp(float x) {
#if __has_builtin(__builtin_amdgcn_rcpf)
    return __builtin_amdgcn_rcpf(x);
#else
    return 1.0f / x;
#endif
}

// correctly-rounded k/99.0f (Markstein 2-fma refinement); same bits whether
// constant-folded (literal k) or evaluated at runtime. z_k bits MUST match
// the reference linspace — never approximate this.
__device__ __forceinline__ float div99(int k) {
    const float c = 1.0f / 99.0f;
    float fk = (float)k;
    float t0 = fk * c;
    float e  = fmaf(t0, -99.0f, fk);
    return fmaf(e, c, t0);
}

__device__ __forceinline__ float zq(int k, float dzr, float smin) {
    return fmaf(div99(k), dzr, smin);
}
__device__ __forceinline__ float qat(float z, float trcd, float cam2) {
    return fmaf(z, z + trcd, cam2);
}

// 1 wave per block. Decoupled s/e chains, packed-f32 trace arithmetic
// (v_pk_fma/v_pk_add; bit-exact per component), one sqrt per chain per iter
// on the SELECTED q (q<1 <=> sdf<0, sign-exact). No fmax before trace sqrts:
// sphere-trace understeps => every evaluated trace point has q >= 1-2ulp.
__global__ __launch_bounds__(64) void raytrace_kernel(
    const float* __restrict__ cam, const float* __restrict__ ray,
    float* __restrict__ out, int N, int nshift, int R)
{
    int tid = blockIdx.x * 64 + threadIdx.x;
    bool aliveLane = tid < R;
    int gid = aliveLane ? tid : (R - 1);   // clamp; all 64 lanes live for coop ops
    int lane = threadIdx.x & 63;
    int b = (nshift >= 0) ? (gid >> nshift) : (gid / N);
    b = __builtin_amdgcn_readfirstlane(b); // wave-uniform -> scalar loads

    float cx = cam[b * 3 + 0], cy = cam[b * 3 + 1], cz = cam[b * 3 + 2];
    float rx = ray[(size_t)gid * 3 + 0], ry = ray[(size_t)gid * 3 + 1], rz = ray[(size_t)gid * 3 + 2];

    float rcd  = rx * cx + ry * cy + rz * cz;
    float cam2 = cx * cx + cy * cy + cz * cz;
    float trcd = rcd + rcd;

    // ---- sphere intersections (OBJ_R = 5); one-time sqrt kept correctly rounded ----
    float under = rcd * rcd - (cam2 - 25.0f);
    bool  m0 = under > 0.0f;
    float sq = sqrtf(m0 ? under : 1.0f);
    float nearv = m0 ? fmaxf(-sq - rcd, 0.0f) : 0.0f;
    float farv  = m0 ? fmaxf( sq - rcd, 0.0f) : 0.0f;

    // ---- decoupled sphere tracing, packed arithmetic ----
    bool  us = m0, ue = m0;
    f32x2 a = { nearv, farv };                         // {as, ae}
    f32x2 n;
    n.x = us ? (fast_sqrtf(qat(a.x, trcd, cam2)) - 1.0f) : 0.0f;
    n.y = ue ? (fast_sqrtf(qat(a.y, trcd, cam2)) - 1.0f) : 0.0f;

    const f32x2 vtrcd = { trcd, trcd };
    const f32x2 vcam2 = { cam2, cam2 };
    const f32x2 sgn   = { 1.0f, -1.0f };
    const f32x2 srcd  = { rcd, -rcd };

    bool  alive = true;                     // joint not-yet-crossed
    float fs = a.x, fe = a.y;               // latched joint positions

    #pragma unroll 1
    for (int i = 0; i < TRACE_ITERS; ++i) {
        bool gs = n.x > SDF_THR, ge = n.y > SDF_THR;
        f32x2 cv;                                      // signed steps {+cs, -ce}
        cv.x = (us && gs) ?  n.x : 0.0f;
        cv.y = (ue && ge) ? -n.y : 0.0f;
        us = us && gs;
        ue = ue && ge;
        f32x2 a_step = a + cv;                         // v_pk_add
        f32x2 a_back = __builtin_elementwise_fma((f32x2)(-0.9f), cv, a_step);
        f32x2 q1 = __builtin_elementwise_fma(a_step, a_step + vtrcd, vcam2);
        f32x2 q2 = __builtin_elementwise_fma(a_back, a_back + vtrcd, vcam2);
        // t = sgn*a_step + sgn*rcd: s-cond rcd+as_step>0; e-cond rcd+ae_step<0
        f32x2 t = __builtin_elementwise_fma(sgn, a_step, srcd);
        bool np_s = (q1.x < 1.0f) || (t.x > 0.0f);     // sdf<0 <=> q<1 (sign-exact)
        bool np_e = (q1.y < 1.0f) || (t.y > 0.0f);
        a.x = np_s ? a_back.x : a_step.x;
        a.y = np_e ? a_back.y : a_step.y;
        float qs = np_s ? q2.x : q1.x;
        float qe = np_e ? q2.y : q1.y;
        n.x = fast_sqrtf(qs) - 1.0f;                   // q >= 1-2ulp: no fmax needed
        n.y = fast_sqrtf(qe) - 1.0f;
        // joint latch (positions only)
        fs = alive ? a.x : fs;
        fe = alive ? a.y : fe;
        alive = alive && (a.x < a.y);
        bool notdone = alive && (us || ue);
        if (!__any(notdone)) break;                    // frozen lanes are no-ops
    }

    // joint final state: unf_s = alive && us; fns recomputed bit-identically
    bool unf_s = alive && us;
    {
        float fns = fast_sqrtf(qat(fs, trcd, cam2)) - 1.0f;   // trace point: q>=1
        float curf = unf_s ? fns : 0.0f;
        curf = (curf <= SDF_THR) ? 0.0f : curf;
        unf_s = unf_s && (curf > SDF_THR);
    }

    // ---- defaults from trace ----
    bool  out_m = fs < fe;
    float out_d = fs;

    float smin = fs, dzr = fe - fs;
    int   dec = 1;            // 1 = no-negative (bk_nonneg), 2 = negative (kneg), 0 = fallback
    int   kneg = 1000;
    float bk_nonneg = 0.0f;

    if (unf_s) {
        // ---- analytic sampler: all decisions on computed q(z_k) vs 1 ----
        float step99 = dzr * (1.0f / 99.0f);
        float rstep  = fast_rcp(step99);    // window centering only (slack >> error)

        // (a) discrete argmin + any-negative: window around the parabola vertex
        float fkv = (-rcd - smin) * rstep;
        fkv = fminf(fmaxf(fkv, 0.0f), 99.0f);
        int kv = (int)fkv;
        float bq = 3.4e38f; float bkf = 0.0f;
        #pragma unroll
        for (int d = -2; d <= 3; ++d) {
            int k = min(max(kv + d, 0), 99);
            float q = qat(zq(k, dzr, smin), trcd, cam2);
            bool better = q < bq;               // strict -> first occurrence
            bq  = better ? q : bq;
            bkf = better ? (float)k : bkf;
        }

        if (fabsf(bq - 1.0f) <= QGUARD) {
            dec = 0;                            // decision inside guard band
        } else if (bq > 1.0f) {
            dec = 1; bk_nonneg = bkf;           // no negative sample anywhere
        } else {
            float q0 = qat(smin, trcd, cam2);   // z_0 == smin exactly
            if (q0 < 1.0f) {
                dec = 2; kneg = 0;
            } else {
                float disc = fmaf(rcd, rcd, 1.0f - cam2);
                float zroot = -rcd - sqrtf(fmaxf(disc, 0.0f));   // left root of q=1
                float fk = (zroot - smin) * rstep;
                fk = fminf(fmaxf(fk, -8.0f), 108.0f);
                int ka = (int)ceilf(fk);
                int kw = 1000;
                #pragma unroll
                for (int d = -3; d <= 3; ++d) {
                    int k = min(max(ka + d, 1), 99);
                    float q = qat(zq(k, dzr, smin), trcd, cam2);
                    kw = (q < 1.0f) ? min(kw, k) : kw;
                }
                if (kw == 1000) {
                    dec = 0;                    // analytic index off -> fallback
                } else {
                    float qprev = qat(zq(kw - 1, dzr, smin), trcd, cam2);
                    if (!(qprev >= 1.0f + QGUARD)) dec = 0;   // contiguity unproven
                    else { dec = 2; kneg = kw; }
                }
            }
        }
    }

    // ---- wave-cooperative fallback: full 100-sample scan as a 64-lane reduction ----
    bool need_fb = unf_s && (dec == 0) && aliveLane;
    unsigned long long fbm = __ballot(need_fb);
    while (fbm) {
        int src = __ffsll((unsigned long long)fbm) - 1;
        fbm &= fbm - 1;
        float s_smin = __shfl(smin, src);
        float s_dzr  = __shfl(dzr,  src);
        float s_trcd = __shfl(trcd, src);
        float s_cam2 = __shfl(cam2, src);
        float q1 = qat(zq(lane, s_dzr, s_smin), s_trcd, s_cam2);
        int   k2 = lane + 64;
        bool  v2 = k2 < N_STEPS;
        float q2 = v2 ? qat(zq(k2, s_dzr, s_smin), s_trcd, s_cam2) : 3.4e38f;
        bool b2 = q2 < q1;                      // strict: tie keeps smaller k
        float mq = b2 ? q2 : q1;
        int   mk = b2 ? k2 : lane;
        int nk = 1000;
        nk = (q1 < 1.0f) ? lane : nk;
        nk = (v2 && q2 < 1.0f) ? min(nk, k2) : nk;
        #pragma unroll
        for (int off = 1; off < 64; off <<= 1) {
            float oq = __shfl_xor(mq, off);
            int   ok = __shfl_xor(mk, off);
            int   on = __shfl_xor(nk, off);
            bool bet = (oq < mq) || ((oq == mq) && (ok < mk));
            mq = bet ? oq : mq;
            mk = bet ? ok : mk;
            nk = min(nk, on);
        }
        if (lane == src) {
            if (nk < 1000) { dec = 2; kneg = nk; }
            else           { dec = 1; bk_nonneg = (float)mk; }
        }
    }

    // ---- final resolution (shared bisection for every kneg producer) ----
    if (unf_s) {
        if (dec == 2) {
            int klo = max(kneg - 1, 0);
            float lo = zq(klo,  dzr, smin);     // kneg==0 -> lo==hi==z0 (matches ref)
            float hi = zq(kneg, dzr, smin);
            #pragma unroll
            for (int it = 0; it < N_ROOTFIND; ++it) {
                float mid = 0.5f * (lo + hi);
                float qm  = qat(mid, trcd, cam2);
                bool go_lo = qm > 1.0f;         // sdf(mid) > 0
                lo = go_lo ? mid : lo;
                hi = go_lo ? hi : mid;
            }
            out_d = 0.5f * (lo + hi);
            out_m = true;
        } else {
            out_d = zq((int)bk_nonneg, dzr, smin);   // min-sdf sample
            out_m = false;
        }
    }

    // ---- outputs: pts [R,3] | net_obj [R] | acc_s [R] ----
    if (aliveLane) {
        out[(size_t)gid * 3 + 0] = fmaf(out_d, rx, cx);
        out[(size_t)gid * 3 + 1] = fmaf(out_d, ry, cy);
        out[(size_t)gid * 3 + 2] = fmaf(out_d, rz, cz);
        out[(size_t)R * 3 + gid] = out_m ? 1.0f : 0.0f;
        out[(size_t)R * 4 + gid] = out_d;
    }
}

extern "C" void kernel_launch(void* const* d_in, const int* in_sizes, int n_in,
                              void* d_out, int out_size, void* d_ws, size_t ws_size,
                              hipStream_t stream) {
    const float* cam = (const float*)d_in[0];
    const float* ray = (const float*)d_in[1];
    int B = in_sizes[0] / 3;
    int R = in_sizes[1] / 3;
    int N = R / B;
    int nshift = -1;
    if ((N & (N - 1)) == 0) { nshift = 0; while ((1 << nshift) != N) ++nshift; }
    int threads = 64;
    int blocks = (R + threads - 1) / threads;
    raytrace_kernel<<<blocks, threads, 0, stream>>>(cam, ray, (float*)d_out, N, nshift, R);
}

// Round 14
// 12.509 us; speedup vs baseline: 1.0054x; 1.0054x over previous
//
#include <hip/hip_runtime.h>

#define SDF_THR 5e-5f
#define TRACE_ITERS 10
#define N_STEPS 100
#define N_ROOTFIND 8
#define QGUARD 1e-5f

// raw v_sqrt_f32 (~1 ulp) — avoids the IEEE fixup sequence
__device__ __forceinline__ float fast_sqrtf(float x) {
#if __has_builtin(__builtin_amdgcn_sqrtf)
    return __builtin_amdgcn_sqrtf(x);
#else
    return sqrtf(x);
#endif
}

// correctly-rounded k/99.0f (Markstein 2-fma refinement); same bits whether
// constant-folded (literal k) or evaluated at runtime.
__device__ __forceinline__ float div99(int k) {
    const float c = 1.0f / 99.0f;
    float fk = (float)k;
    float t0 = fk * c;
    float e  = fmaf(t0, -99.0f, fk);
    return fmaf(e, c, t0);
}

__device__ __forceinline__ float zq(int k, float dzr, float smin) {
    return fmaf(div99(k), dzr, smin);
}
__device__ __forceinline__ float qat(float z, float trcd, float cam2) {
    return fmaf(z, z + trcd, cam2);
}
// sdf(cam + a*ray) with |ray|=1:  q(a) = a^2 + 2a*rcd + cam2
__device__ __forceinline__ float sdfq(float a, float trcd, float cam2) {
    return fast_sqrtf(fmaxf(qat(a, trcd, cam2), 0.0f)) - 1.0f;
}

// 1 wave per block. Decoupled s/e chains; ONE sqrt per chain per iteration:
// the line-search decision is made on q (q<1 <=> sdf<0, sign-exact), both
// candidate q's are cheap parallel fmas, and the single sqrt evaluates only
// the SELECTED candidate — bit-identical values, half the transcendental
// issue. fns/ufs latches deleted (provably redundant: unf_s = alive && us,
// and when alive fs==as so fns is recomputable post-loop bit-identically).
__global__ __launch_bounds__(64) void raytrace_kernel(
    const float* __restrict__ cam, const float* __restrict__ ray,
    float* __restrict__ out, int N, int nshift, int R)
{
    int tid = blockIdx.x * 64 + threadIdx.x;
    bool aliveLane = tid < R;
    int gid = aliveLane ? tid : (R - 1);   // clamp; all 64 lanes live for coop ops
    int lane = threadIdx.x & 63;
    int b = (nshift >= 0) ? (gid >> nshift) : (gid / N);
    b = __builtin_amdgcn_readfirstlane(b); // wave-uniform in reality -> scalar loads

    float cx = cam[b * 3 + 0], cy = cam[b * 3 + 1], cz = cam[b * 3 + 2];
    float rx = ray[(size_t)gid * 3 + 0], ry = ray[(size_t)gid * 3 + 1], rz = ray[(size_t)gid * 3 + 2];

    float rcd  = rx * cx + ry * cy + rz * cz;
    float cam2 = cx * cx + cy * cy + cz * cz;
    float trcd = rcd + rcd;

    // ---- sphere intersections (OBJ_R = 5); one-time sqrt kept correctly rounded ----
    float under = rcd * rcd - (cam2 - 25.0f);
    bool  m0 = under > 0.0f;
    float sq = sqrtf(m0 ? under : 1.0f);
    float nearv = m0 ? fmaxf(-sq - rcd, 0.0f) : 0.0f;
    float farv  = m0 ? fmaxf( sq - rcd, 0.0f) : 0.0f;

    // ---- decoupled sphere tracing, 1 sqrt / chain / iter ----
    bool  us = m0, ue = m0;
    float as = nearv, ae = farv;
    float ns = us ? sdfq(as, trcd, cam2) : 0.0f;
    float ne = ue ? sdfq(ae, trcd, cam2) : 0.0f;

    bool  alive = true;                     // joint not-yet-crossed
    float fs = as, fe = ae;                 // latched joint positions

    #pragma unroll 1
    for (int i = 0; i < TRACE_ITERS; ++i) {
        // ---- s-chain ----
        bool  gs = ns > SDF_THR;
        float cs = (us && gs) ? ns : 0.0f;
        us = us && gs;
        float as_step = as + cs;
        float as_back = fmaf(-0.9f, cs, as_step);        // == as_step when cs==0
        float q1s = qat(as_step, trcd, cam2);
        float q2s = qat(as_back, trcd, cam2);            // parallel fma
        bool np_s = (q1s < 1.0f) || (rcd + as_step > 0.0f);  // sdf<0 <=> q<1 exact
        as = np_s ? as_back : as_step;
        float qs = np_s ? q2s : q1s;
        ns = fast_sqrtf(fmaxf(qs, 0.0f)) - 1.0f;         // single sqrt on selected q
        // ---- e-chain ----
        bool  ge = ne > SDF_THR;
        float ce = (ue && ge) ? ne : 0.0f;
        ue = ue && ge;
        float ae_step = ae - ce;
        float ae_back = fmaf(0.9f, ce, ae_step);
        float q1e = qat(ae_step, trcd, cam2);
        float q2e = qat(ae_back, trcd, cam2);            // parallel fma
        bool np_e = (q1e < 1.0f) || (rcd + ae_step < 0.0f);
        ae = np_e ? ae_back : ae_step;
        float qe = np_e ? q2e : q1e;
        ne = fast_sqrtf(fmaxf(qe, 0.0f)) - 1.0f;         // single sqrt on selected q
        // ---- joint latch (positions only) ----
        fs = alive ? as : fs;
        fe = alive ? ae : fe;
        alive = alive && (as < ae);
        bool notdone = alive && (us || ue);
        if (!__any(notdone)) break;          // bit-exact: frozen lanes are no-ops
    }

    // joint final state: unf_s = alive && us (ufs latch provably redundant),
    // fns recomputed bit-identically (when alive, fs == as).
    bool unf_s = alive && us;
    {
        float fns = sdfq(fs, trcd, cam2);
        float curf = unf_s ? fns : 0.0f;
        curf = (curf <= SDF_THR) ? 0.0f : curf;
        unf_s = unf_s && (curf > SDF_THR);
    }

    // ---- defaults from trace ----
    bool  out_m = fs < fe;
    float out_d = fs;

    float smin = fs, dzr = fe - fs;
    int   dec = 1;            // 1 = no-negative (bk_nonneg), 2 = negative (kneg), 0 = fallback
    int   kneg = 1000;
    float bk_nonneg = 0.0f;

    if (unf_s) {
        // ---- analytic sampler: all decisions on computed q(z_k) vs 1 ----
        float step99 = dzr * (1.0f / 99.0f);

        // (a) discrete argmin + any-negative: window around the parabola vertex
        float fkv = (-rcd - smin) / step99;
        fkv = fminf(fmaxf(fkv, 0.0f), 99.0f);
        int kv = (int)fkv;
        float bq = 3.4e38f; float bkf = 0.0f;
        #pragma unroll
        for (int d = -2; d <= 3; ++d) {
            int k = min(max(kv + d, 0), 99);
            float q = qat(zq(k, dzr, smin), trcd, cam2);
            bool better = q < bq;               // strict -> first occurrence
            bq  = better ? q : bq;
            bkf = better ? (float)k : bkf;
        }

        if (fabsf(bq - 1.0f) <= QGUARD) {
            dec = 0;                            // decision inside guard band
        } else if (bq > 1.0f) {
            dec = 1; bk_nonneg = bkf;           // no negative sample anywhere
        } else {
            float q0 = qat(smin, trcd, cam2);   // z_0 == smin exactly
            if (q0 < 1.0f) {
                dec = 2; kneg = 0;
            } else {
                float disc = fmaf(rcd, rcd, 1.0f - cam2);
                float zroot = -rcd - sqrtf(fmaxf(disc, 0.0f));   // left root of q=1
                float fk = (zroot - smin) / step99;
                fk = fminf(fmaxf(fk, -8.0f), 108.0f);
                int ka = (int)ceilf(fk);
                int kw = 1000;
                #pragma unroll
                for (int d = -3; d <= 3; ++d) {
                    int k = min(max(ka + d, 1), 99);
                    float q = qat(zq(k, dzr, smin), trcd, cam2);
                    kw = (q < 1.0f) ? min(kw, k) : kw;
                }
                if (kw == 1000) {
                    dec = 0;                    // analytic index off -> fallback
                } else {
                    float qprev = qat(zq(kw - 1, dzr, smin), trcd, cam2);
                    if (!(qprev >= 1.0f + QGUARD)) dec = 0;   // contiguity unproven
                    else { dec = 2; kneg = kw; }
                }
            }
        }
    }

    // ---- wave-cooperative fallback: full 100-sample scan as a 64-lane reduction ----
    bool need_fb = unf_s && (dec == 0) && aliveLane;
    unsigned long long fbm = __ballot(need_fb);
    while (fbm) {
        int src = __ffsll((unsigned long long)fbm) - 1;
        fbm &= fbm - 1;
        float s_smin = __shfl(smin, src);
        float s_dzr  = __shfl(dzr,  src);
        float s_trcd = __shfl(trcd, src);
        float s_cam2 = __shfl(cam2, src);
        float q1 = qat(zq(lane, s_dzr, s_smin), s_trcd, s_cam2);
        int   k2 = lane + 64;
        bool  v2 = k2 < N_STEPS;
        float q2 = v2 ? qat(zq(k2, s_dzr, s_smin), s_trcd, s_cam2) : 3.4e38f;
        bool b2 = q2 < q1;                      // strict: tie keeps smaller k
        float mq = b2 ? q2 : q1;
        int   mk = b2 ? k2 : lane;
        int nk = 1000;
        nk = (q1 < 1.0f) ? lane : nk;
        nk = (v2 && q2 < 1.0f) ? min(nk, k2) : nk;
        #pragma unroll
        for (int off = 1; off < 64; off <<= 1) {
            float oq = __shfl_xor(mq, off);
            int   ok = __shfl_xor(mk, off);
            int   on = __shfl_xor(nk, off);
            bool bet = (oq < mq) || ((oq == mq) && (ok < mk));
            mq = bet ? oq : mq;
            mk = bet ? ok : mk;
            nk = min(nk, on);
        }
        if (lane == src) {
            if (nk < 1000) { dec = 2; kneg = nk; }
            else           { dec = 1; bk_nonneg = (float)mk; }
        }
    }

    // ---- final resolution (shared bisection for every kneg producer) ----
    if (unf_s) {
        if (dec == 2) {
            int klo = max(kneg - 1, 0);
            float lo = zq(klo,  dzr, smin);     // kneg==0 -> lo==hi==z0 (matches ref)
            float hi = zq(kneg, dzr, smin);
            #pragma unroll
            for (int it = 0; it < N_ROOTFIND; ++it) {
                float mid = 0.5f * (lo + hi);
                float qm  = qat(mid, trcd, cam2);
                bool go_lo = qm > 1.0f;         // sdf(mid) > 0
                lo = go_lo ? mid : lo;
                hi = go_lo ? hi : mid;
            }
            out_d = 0.5f * (lo + hi);
            out_m = true;
        } else {
            out_d = zq((int)bk_nonneg, dzr, smin);   // min-sdf sample
            out_m = false;
        }
    }

    // ---- outputs: pts [R,3] | net_obj [R] | acc_s [R] ----
    if (aliveLane) {
        out[(size_t)gid * 3 + 0] = fmaf(out_d, rx, cx);
        out[(size_t)gid * 3 + 1] = fmaf(out_d, ry, cy);
        out[(size_t)gid * 3 + 2] = fmaf(out_d, rz, cz);
        out[(size_t)R * 3 + gid] = out_m ? 1.0f : 0.0f;
        out[(size_t)R * 4 + gid] = out_d;
    }
}

extern "C" void kernel_launch(void* const* d_in, const int* in_sizes, int n_in,
                              void* d_out, int out_size, void* d_ws, size_t ws_size,
                              hipStream_t stream) {
    const float* cam = (const float*)d_in[0];
    const float* ray = (const float*)d_in[1];
    int B = in_sizes[0] / 3;
    int R = in_sizes[1] / 3;
    int N = R / B;
    int nshift = -1;
    if ((N & (N - 1)) == 0) { nshift = 0; while ((1 << nshift) != N) ++nshift; }
    int threads = 64;
    int blocks = (R + threads - 1) / threads;
    raytrace_kernel<<<blocks, threads, 0, stream>>>(cam, ray, (float*)d_out, N, nshift, R);
}